// Round 1
// baseline (567.197 us; speedup 1.0000x reference)
//
#include <hip/hip_runtime.h>
#include <stdint.h>

#define BATCH 32768
#define NN    2500
#define NPAD  2560
#define DIM   256

#define BM 128
#define BN 128
#define BK 64
#define LDA 72   // 64 + 8 bf16 pad -> 2-way LDS bank aliasing (free), keeps 16B align

typedef __attribute__((ext_vector_type(8))) short short8;
typedef __attribute__((ext_vector_type(4))) float float4_;

__device__ __forceinline__ unsigned short f2bf(float f) {
  union { float f; uint32_t u; } v; v.f = f;
  uint32_t u = v.u;
  return (unsigned short)((u + 0x7FFFu + ((u >> 16) & 1u)) >> 16);
}

// one wave per row: row-sum of squares, fp32 exact
__global__ void row_sq_norm(const float* __restrict__ in, float* __restrict__ out,
                            int nrows, int nvalid) {
  int row  = blockIdx.x * 4 + (threadIdx.x >> 6);
  int lane = threadIdx.x & 63;
  if (row >= nrows) return;
  float s = 0.f;
  if (row < nvalid) {
    const float4* p = (const float4*)(in + (size_t)row * DIM);
    float4 v = p[lane];                       // 64 lanes x float4 = 256 elems
    s = v.x * v.x + v.y * v.y + v.z * v.z + v.w * v.w;
  }
  for (int off = 32; off > 0; off >>= 1) s += __shfl_down(s, off, 64);
  if (lane == 0) out[row] = s;
}

__global__ __launch_bounds__(256, 2)
void cdist_gemm(const float* __restrict__ X, const float* __restrict__ W,
                const float* __restrict__ xsq, const float* __restrict__ wsq,
                float* __restrict__ out) {
  __shared__ __align__(16) unsigned short As[BM * LDA];
  __shared__ __align__(16) unsigned short Bs[BN * LDA];

  const int tid  = threadIdx.x;
  const int m0   = blockIdx.x * BM;
  const int n0   = blockIdx.y * BN;
  const int lane = tid & 63;
  const int wave = tid >> 6;
  const int wr   = wave >> 1;   // wave row (0..1) -> 64 rows
  const int wc   = wave & 1;    // wave col (0..1) -> 64 cols

  float4_ acc[4][4] = {};

  // staging pattern: 256 threads, each does 8 float4 loads
  const int s_col4 = tid & 15;   // float4 column within BK=64 (16 float4s)
  const int s_row0 = tid >> 4;   // 0..15

  for (int kc = 0; kc < DIM; kc += BK) {
#pragma unroll
    for (int j = 0; j < 8; ++j) {
      int r = s_row0 + 16 * j;
      float4 v = *(const float4*)(X + (size_t)(m0 + r) * DIM + kc + s_col4 * 4);
      *(ushort4*)&As[r * LDA + s_col4 * 4] =
          make_ushort4(f2bf(v.x), f2bf(v.y), f2bf(v.z), f2bf(v.w));
    }
#pragma unroll
    for (int j = 0; j < 8; ++j) {
      int r = s_row0 + 16 * j;
      int n = n0 + r;
      float4 v = make_float4(0.f, 0.f, 0.f, 0.f);
      if (n < NN) v = *(const float4*)(W + (size_t)n * DIM + kc + s_col4 * 4);
      *(ushort4*)&Bs[r * LDA + s_col4 * 4] =
          make_ushort4(f2bf(v.x), f2bf(v.y), f2bf(v.z), f2bf(v.w));
    }
    __syncthreads();

    const int q = lane >> 4;     // quad 0..3
    const int i = lane & 15;
#pragma unroll
    for (int ks = 0; ks < BK; ks += 32) {
      short8 a[4], b[4];
#pragma unroll
      for (int t = 0; t < 4; ++t) {
        a[t] = *(const short8*)&As[(wr * 64 + t * 16 + i) * LDA + ks + q * 8];
        b[t] = *(const short8*)&Bs[(wc * 64 + t * 16 + i) * LDA + ks + q * 8];
      }
#pragma unroll
      for (int ti = 0; ti < 4; ++ti)
#pragma unroll
        for (int tj = 0; tj < 4; ++tj)
          acc[ti][tj] = __builtin_amdgcn_mfma_f32_16x16x32_bf16(
              a[ti], b[tj], acc[ti][tj], 0, 0, 0);
    }
    __syncthreads();
  }

  // epilogue: d = sqrt(max(xsq + wsq - 2*cross, 0))
  // C/D layout: col = lane&15, row = (lane>>4)*4 + reg   [measured m89/m91]
  const int q = lane >> 4;
  const int i = lane & 15;
#pragma unroll
  for (int ti = 0; ti < 4; ++ti) {
    int grow_base = m0 + wr * 64 + ti * 16 + q * 4;
#pragma unroll
    for (int tj = 0; tj < 4; ++tj) {
      int gcol = n0 + wc * 64 + tj * 16 + i;
      if (gcol < NN) {
        float wn = wsq[gcol];
#pragma unroll
        for (int r = 0; r < 4; ++r) {
          int grow = grow_base + r;
          float d2 = xsq[grow] + wn - 2.0f * acc[ti][tj][r];
          out[(size_t)grow * NN + gcol] = sqrtf(fmaxf(d2, 0.f));
        }
      }
    }
  }
}

extern "C" void kernel_launch(void* const* d_in, const int* in_sizes, int n_in,
                              void* d_out, int out_size, void* d_ws, size_t ws_size,
                              hipStream_t stream) {
  const float* x = (const float*)d_in[0];
  const float* w = (const float*)d_in[1];
  float* xsq = (float*)d_ws;          // [BATCH]
  float* wsq = xsq + BATCH;           // [NPAD], zeros for n >= NN

  row_sq_norm<<<BATCH / 4, 256, 0, stream>>>(x, xsq, BATCH, BATCH);
  row_sq_norm<<<NPAD / 4, 256, 0, stream>>>(w, wsq, NPAD, NN);

  dim3 grid(BATCH / BM, NPAD / BN);   // 256 x 20
  cdist_gemm<<<grid, 256, 0, stream>>>(x, w, xsq, wsq, (float*)d_out);
}

// Round 2
// 467.722 us; speedup vs baseline: 1.2127x; 1.2127x over previous
//
#include <hip/hip_runtime.h>
#include <stdint.h>

#define BATCH 32768
#define NN    2500
#define NPAD  2560
#define DIM   256

#define BM 128
#define BN 128
#define BK 64

typedef __attribute__((ext_vector_type(8))) short short8;
typedef __attribute__((ext_vector_type(4))) float float4_;

__device__ __forceinline__ unsigned short f2bf(float f) {
  union { float f; uint32_t u; } v; v.f = f;
  uint32_t u = v.u;
  return (unsigned short)((u + 0x7FFFu + ((u >> 16) & 1u)) >> 16);
}

__device__ __forceinline__ void gload_lds16(const void* g, void* lds) {
  __builtin_amdgcn_global_load_lds(
      (const __attribute__((address_space(1))) unsigned int*)g,
      (__attribute__((address_space(3))) unsigned int*)lds, 16, 0, 0);
}

// ---------------- prep: fp32 -> bf16 copy + exact fp32 row norm ----------------
// one wave per row; rows >= nvalid are zero-filled (for W padding to NPAD)
__global__ void prep_rows(const float* __restrict__ in, unsigned short* __restrict__ outb,
                          float* __restrict__ sq, int nrows, int nvalid) {
  int row  = blockIdx.x * 4 + (threadIdx.x >> 6);
  int lane = threadIdx.x & 63;
  if (row >= nrows) return;
  float4 v = make_float4(0.f, 0.f, 0.f, 0.f);
  if (row < nvalid) v = ((const float4*)(in + (size_t)row * DIM))[lane];
  float s = v.x * v.x + v.y * v.y + v.z * v.z + v.w * v.w;
  *(ushort4*)(outb + (size_t)row * DIM + lane * 4) =
      make_ushort4(f2bf(v.x), f2bf(v.y), f2bf(v.z), f2bf(v.w));
  for (int off = 32; off > 0; off >>= 1) s += __shfl_down(s, off, 64);
  if (lane == 0) sq[row] = s;
}

// ---------------- main GEMM: bf16 in, global_load_lds staging, XOR swizzle ----------------
// LDS tile: 128 rows x 64 bf16, 16B chunks; physical chunk(r, pc) holds logical
// chunk c8 = pc ^ (r&7)  -> ds_read_b128 fragment reads are bank-conflict free
// without padding (global_load_lds forbids padded layouts: dest = base + lane*16).
__global__ __launch_bounds__(256, 4)
void cdist_gemm_bf16(const unsigned short* __restrict__ Xb,
                     const unsigned short* __restrict__ Wb,
                     const float* __restrict__ xsq, const float* __restrict__ wsq,
                     float* __restrict__ out) {
  __shared__ __align__(16) unsigned short As[BM * BK];
  __shared__ __align__(16) unsigned short Bs[BN * BK];

  const int tid  = threadIdx.x;
  const int lane = tid & 63;
  const int wave = tid >> 6;
  const int m0   = blockIdx.x * BM;
  const int n0   = blockIdx.y * BN;
  const int wr   = wave >> 1;
  const int wc   = wave & 1;

  float4_ acc[4][4] = {};

  // staging: wave w handles windows w*4..w*4+3; window = 8 rows x 64 cols = 1KB
  const int lr  = lane >> 3;        // row within window (0..7)
  const int cc  = lane & 7;         // 16B chunk within row (0..7)
  const int csw = cc ^ lr;          // swizzled source chunk

  const unsigned short* gA = Xb + (size_t)(m0 + wave * 32 + lr) * DIM + csw * 8;
  const unsigned short* gB = Wb + (size_t)(n0 + wave * 32 + lr) * DIM + csw * 8;

  const int q = lane >> 4;          // quad 0..3
  const int i = lane & 15;

  for (int kc = 0; kc < DIM; kc += BK) {
#pragma unroll
    for (int t = 0; t < 4; ++t) {
      int win = wave * 4 + t;
      gload_lds16(gA + (size_t)(t * 8) * DIM + kc, &As[win * 512]);
      gload_lds16(gB + (size_t)(t * 8) * DIM + kc, &Bs[win * 512]);
    }
    __syncthreads();

#pragma unroll
    for (int ks4 = 0; ks4 < 2; ++ks4) {      // two K-steps of 32 (4 chunks each)
      short8 a[4], b[4];
#pragma unroll
      for (int t = 0; t < 4; ++t) {
        int r  = t * 16 + i;                 // r&7 == i&7 (base multiple of 16)
        int ca = (ks4 * 4 + q) ^ (i & 7);
        a[t] = *(const short8*)&As[(wr * 64 + r) * 64 + ca * 8];
        b[t] = *(const short8*)&Bs[(wc * 64 + r) * 64 + ca * 8];
      }
#pragma unroll
      for (int ti = 0; ti < 4; ++ti)
#pragma unroll
        for (int tj = 0; tj < 4; ++tj)
          acc[ti][tj] = __builtin_amdgcn_mfma_f32_16x16x32_bf16(
              a[ti], b[tj], acc[ti][tj], 0, 0, 0);
    }
    __syncthreads();
  }

  // epilogue: d = sqrt(max(xsq + wsq - 2*cross, 0))
  // C/D layout: col = lane&15, row = (lane>>4)*4 + reg  [m89/m91]
#pragma unroll
  for (int ti = 0; ti < 4; ++ti) {
    int grow_base = m0 + wr * 64 + ti * 16 + q * 4;
#pragma unroll
    for (int tj = 0; tj < 4; ++tj) {
      int gcol = n0 + wc * 64 + tj * 16 + i;
      if (gcol < NN) {
        float wn = wsq[gcol];
#pragma unroll
        for (int r = 0; r < 4; ++r) {
          int grow = grow_base + r;
          float d2 = xsq[grow] + wn - 2.0f * acc[ti][tj][r];
          out[(size_t)grow * NN + gcol] = sqrtf(fmaxf(d2, 0.f));
        }
      }
    }
  }
}

// ---------------- fallback path (ws too small): round-1 kernels ----------------
#define LDA 72
__global__ void row_sq_norm(const float* __restrict__ in, float* __restrict__ out,
                            int nrows, int nvalid) {
  int row  = blockIdx.x * 4 + (threadIdx.x >> 6);
  int lane = threadIdx.x & 63;
  if (row >= nrows) return;
  float s = 0.f;
  if (row < nvalid) {
    float4 v = ((const float4*)(in + (size_t)row * DIM))[lane];
    s = v.x * v.x + v.y * v.y + v.z * v.z + v.w * v.w;
  }
  for (int off = 32; off > 0; off >>= 1) s += __shfl_down(s, off, 64);
  if (lane == 0) out[row] = s;
}

__global__ __launch_bounds__(256, 2)
void cdist_gemm_f32(const float* __restrict__ X, const float* __restrict__ W,
                    const float* __restrict__ xsq, const float* __restrict__ wsq,
                    float* __restrict__ out) {
  __shared__ __align__(16) unsigned short As[BM * LDA];
  __shared__ __align__(16) unsigned short Bs[BN * LDA];
  const int tid = threadIdx.x, lane = tid & 63, wave = tid >> 6;
  const int m0 = blockIdx.x * BM, n0 = blockIdx.y * BN;
  const int wr = wave >> 1, wc = wave & 1;
  float4_ acc[4][4] = {};
  const int s_col4 = tid & 15, s_row0 = tid >> 4;
  for (int kc = 0; kc < DIM; kc += BK) {
#pragma unroll
    for (int j = 0; j < 8; ++j) {
      int r = s_row0 + 16 * j;
      float4 v = *(const float4*)(X + (size_t)(m0 + r) * DIM + kc + s_col4 * 4);
      *(ushort4*)&As[r * LDA + s_col4 * 4] =
          make_ushort4(f2bf(v.x), f2bf(v.y), f2bf(v.z), f2bf(v.w));
    }
#pragma unroll
    for (int j = 0; j < 8; ++j) {
      int r = s_row0 + 16 * j, n = n0 + r;
      float4 v = make_float4(0.f, 0.f, 0.f, 0.f);
      if (n < NN) v = *(const float4*)(W + (size_t)n * DIM + kc + s_col4 * 4);
      *(ushort4*)&Bs[r * LDA + s_col4 * 4] =
          make_ushort4(f2bf(v.x), f2bf(v.y), f2bf(v.z), f2bf(v.w));
    }
    __syncthreads();
    const int q = lane >> 4, i = lane & 15;
#pragma unroll
    for (int ks = 0; ks < BK; ks += 32) {
      short8 a[4], b[4];
#pragma unroll
      for (int t = 0; t < 4; ++t) {
        a[t] = *(const short8*)&As[(wr * 64 + t * 16 + i) * LDA + ks + q * 8];
        b[t] = *(const short8*)&Bs[(wc * 64 + t * 16 + i) * LDA + ks + q * 8];
      }
#pragma unroll
      for (int ti = 0; ti < 4; ++ti)
#pragma unroll
        for (int tj = 0; tj < 4; ++tj)
          acc[ti][tj] = __builtin_amdgcn_mfma_f32_16x16x32_bf16(
              a[ti], b[tj], acc[ti][tj], 0, 0, 0);
    }
    __syncthreads();
  }
  const int q = lane >> 4, i = lane & 15;
#pragma unroll
  for (int ti = 0; ti < 4; ++ti) {
    int grow_base = m0 + wr * 64 + ti * 16 + q * 4;
#pragma unroll
    for (int tj = 0; tj < 4; ++tj) {
      int gcol = n0 + wc * 64 + tj * 16 + i;
      if (gcol < NN) {
        float wn = wsq[gcol];
#pragma unroll
        for (int r = 0; r < 4; ++r) {
          int grow = grow_base + r;
          float d2 = xsq[grow] + wn - 2.0f * acc[ti][tj][r];
          out[(size_t)grow * NN + gcol] = sqrtf(fmaxf(d2, 0.f));
        }
      }
    }
  }
}

extern "C" void kernel_launch(void* const* d_in, const int* in_sizes, int n_in,
                              void* d_out, int out_size, void* d_ws, size_t ws_size,
                              hipStream_t stream) {
  const float* x = (const float*)d_in[0];
  const float* w = (const float*)d_in[1];

  const size_t xb_elems = (size_t)BATCH * DIM;          // bf16
  const size_t wb_elems = (size_t)NPAD * DIM;           // bf16
  const size_t need = xb_elems * 2 + wb_elems * 2 + (size_t)BATCH * 4 + (size_t)NPAD * 4;

  if (ws_size >= need) {
    unsigned short* Xb = (unsigned short*)d_ws;
    unsigned short* Wb = Xb + xb_elems;
    float* xsq = (float*)(Wb + wb_elems);
    float* wsq = xsq + BATCH;

    prep_rows<<<BATCH / 4, 256, 0, stream>>>(x, Xb, xsq, BATCH, BATCH);
    prep_rows<<<NPAD / 4, 256, 0, stream>>>(w, Wb, wsq, NPAD, NN);

    dim3 grid(BATCH / BM, NPAD / BN);
    cdist_gemm_bf16<<<grid, 256, 0, stream>>>(Xb, Wb, xsq, wsq, (float*)d_out);
  } else {
    float* xsq = (float*)d_ws;
    float* wsq = xsq + BATCH;
    row_sq_norm<<<BATCH / 4, 256, 0, stream>>>(x, xsq, BATCH, BATCH);
    row_sq_norm<<<NPAD / 4, 256, 0, stream>>>(w, wsq, NPAD, NN);
    dim3 grid(BATCH / BM, NPAD / BN);
    cdist_gemm_f32<<<grid, 256, 0, stream>>>(x, w, xsq, wsq, (float*)d_out);
  }
}